// Round 14
// baseline (43750.748 us; speedup 1.0000x reference)
//
#include <hip/hip_runtime.h>

#define NN    500
#define TT    20000
#define NPAD  512
#define NBLK  8
#define NROW  64        // padded rows per block
#define TPB   512
#define RPT   4         // rows per thread
#define CPT   16        // cols per thread (strided by 32)
#define KB    8         // steps per batch (noise/out bursts)
#define DTC   0.05f
#define SQDTC 0.22360679774997896f

typedef unsigned int u32x4 __attribute__((ext_vector_type(4)));
typedef float        f32x2 __attribute__((ext_vector_type(2)));

// ---------------------------------------------------------------------------
// Fully-coherent 16B accessors (sc0 sc1, proven R2/R5). Packet (x,tag,y,tag):
// each 8B half = one data word + one tag copy.
// ---------------------------------------------------------------------------
__device__ __forceinline__ void store_coh_u128(u32x4* p, u32x4 v) {
    asm volatile("global_store_dwordx4 %0, %1, off sc0 sc1" :: "v"(p), "v"(v) : "memory");
}
__device__ __forceinline__ u32x4 load_coh_u128(const u32x4* p) {
    u32x4 v;
    asm volatile("global_load_dwordx4 %0, %1, off sc0 sc1\n\t"
                 "s_waitcnt vmcnt(0)" : "=v"(v) : "v"(p) : "memory");
    return v;
}
// plain cached 8B load, issued at program point, NO implicit wait — the
// caller's explicit vmcnt(0) drain covers it before any use.
__device__ __forceinline__ void load_async_f2(f32x2* dst, const float* p) {
    asm volatile("global_load_dwordx2 %0, %1, off" : "=v"(*dst) : "v"(p) : "memory");
}

// ws layout: pub[2][NPAD] of u32x4 = 16 KB
__global__ __launch_bounds__(1024) void hopf_init_ws(u32x4* pub) {
    int i = blockIdx.x * blockDim.x + threadIdx.x;
    if (i < 2 * NPAD) pub[i] = (u32x4){0u, 0u, 0u, 0u};
}

__global__ __launch_bounds__(TPB) void hopf_main(
    const float* __restrict__ sc, const float* __restrict__ x0,
    const float* __restrict__ y0, const float* __restrict__ aa,
    const float* __restrict__ om, const float* __restrict__ noise,
    const float* __restrict__ gg, float* __restrict__ out,
    u32x4* __restrict__ pub)
{
    const int tid  = threadIdx.x;
    const int blk  = blockIdx.x;
    const int cgrp = tid & 31;       // 32 column groups
    const int rgrp = tid >> 5;       // 16 row groups of RPT rows
    const int r0   = blk * NROW + rgrp * RPT;   // padded global row base

    __shared__ __align__(16) float2 xy[NPAD];   // full padded state (x,y)
    __shared__ __align__(16) float2 own[NROW];  // own rows bypass (LDS)

    // ---- sc slice -> registers.  col(c) = cgrp + 32*c ----
    float scr[RPT][CPT];
#pragma unroll
    for (int r = 0; r < RPT; ++r) {
        int row = r0 + r;
#pragma unroll
        for (int c = 0; c < CPT; ++c) {
            int col = cgrp + 32 * c;
            scr[r][c] = (row < NN && col < NN) ? sc[row * NN + col] : 0.0f;
        }
    }

    // ---- deg per row ----
    float dsum[RPT];
#pragma unroll
    for (int r = 0; r < RPT; ++r) {
        float s = 0.f;
#pragma unroll
        for (int c = 0; c < CPT; ++c) s += scr[r][c];
        dsum[r] = s;
    }
#pragma unroll
    for (int m = 16; m >= 1; m >>= 1) {
#pragma unroll
        for (int r = 0; r < RPT; ++r) dsum[r] += __shfl_xor(dsum[r], m, 32);
    }

    // ---- pin the sc slice ----
#pragma unroll
    for (int r = 0; r < RPT; ++r)
#pragma unroll
        for (int c = 0; c < CPT; ++c)
            asm volatile("" : "+v"(scr[r][c]));

    // ---- per-finalize-lane constants (lanes cgrp<RPT own row r0+cgrp) ----
    float a_i = 0.f, om_i = 0.f, deg_i = 0.f;
    int myrow = -1;
    if (cgrp < RPT) {
        int row = r0 + cgrp;
        deg_i = (cgrp == 0) ? dsum[0] : (cgrp == 1) ? dsum[1]
              : (cgrp == 2) ? dsum[2] : dsum[3];
        if (row < NN) { myrow = row; a_i = aa[row]; om_i = om[row]; }
    }
    const float g = gg[0];
    const int obase = blk * NROW;

    // noise row base (clamped, harmless for non-publisher lanes)
    const float* nrow = noise + 2 * (size_t)(myrow >= 0 ? myrow : 0);

    // ---- initial state into LDS (pad rows stay zero forever) ----
    xy[tid] = (tid < NN) ? make_float2(x0[tid], y0[tid]) : make_float2(0.f, 0.f);
    __syncthreads();

    for (int tb = 0; tb < TT; tb += KB) {
        // ---- noise burst: 8 async loads for steps tb..tb+7 (overlap matvec#0;
        //      drained once at the k==0 pre-finalize drain) ----
        f32x2 nzb[KB];
#pragma unroll
        for (int k = 0; k < KB; ++k)
            load_async_f2(&nzb[k], nrow + (size_t)(tb + k) * (2 * NN));

        float xnb[KB];

#pragma unroll
        for (int k = 0; k < KB; ++k) {
            const int t = tb + k;
            const int p = t & 1;

            // ---- partial matvec: 4 rows x 16 strided cols per thread ----
            float2 acc[RPT];
#pragma unroll
            for (int r = 0; r < RPT; ++r) acc[r] = make_float2(0.f, 0.f);
#pragma unroll
            for (int c = 0; c < CPT; ++c) {
                float2 w = xy[cgrp + 32 * c];
#pragma unroll
                for (int r = 0; r < RPT; ++r) {
                    acc[r].x += scr[r][c] * w.x;
                    acc[r].y += scr[r][c] * w.y;
                }
            }
#pragma unroll
            for (int m = 16; m >= 1; m >>= 1) {
#pragma unroll
                for (int r = 0; r < RPT; ++r) {
                    acc[r].x += __shfl_xor(acc[r].x, m, 32);
                    acc[r].y += __shfl_xor(acc[r].y, m, 32);
                }
            }

            // single drain per 8 steps: noise burst + prev block's out burst.
            // After this, the vmem queue during polls = {pub store, poll load}.
            if (k == 0) asm volatile("s_waitcnt vmcnt(0)" ::: "memory");

            // ---- finalize + publish tagged 16B packet (lanes cgrp<RPT) ----
            if (myrow >= 0) {
                float sx = (cgrp == 0) ? acc[0].x : (cgrp == 1) ? acc[1].x
                         : (cgrp == 2) ? acc[2].x : acc[3].x;
                float sy = (cgrp == 0) ? acc[0].y : (cgrp == 1) ? acc[1].y
                         : (cgrp == 2) ? acc[2].y : acc[3].y;
                float2 cur = xy[myrow];
                float r2 = cur.x * cur.x + cur.y * cur.y;
                float cx = sx - deg_i * cur.x;
                float cy = sy - deg_i * cur.y;
                float dx = (a_i - r2) * cur.x - om_i * cur.y + g * cx;
                float dy = (a_i - r2) * cur.y + om_i * cur.x + g * cy;
                float xn = cur.x + DTC * dx + SQDTC * nzb[k].x;
                float yn = cur.y + DTC * dy + SQDTC * nzb[k].y;
                xnb[k] = xn;
                u32x4 pkt = { __float_as_uint(xn), (unsigned)(t + 1),
                              __float_as_uint(yn), (unsigned)(t + 1) };
                store_coh_u128(&pub[(size_t)p * NPAD + myrow], pkt);
                own[myrow - obase] = make_float2(xn, yn);
            }

            if (t < TT - 1) {
                // protect xy reads; also makes own[] visible block-wide
                __syncthreads();

                // ---- gather: own rows from LDS; foreign rows via poll ----
                if (tid < NN) {
                    if (tid >= obase && tid < obase + NROW) {
                        xy[tid] = own[tid - obase];
                    } else {
                        const u32x4* slot = &pub[(size_t)p * NPAD + tid];
                        u32x4 v;
                        do {
                            v = load_coh_u128(slot);
                        } while ((int)v.y < t + 1 || (int)v.w < t + 1);
                        xy[tid] = make_float2(__uint_as_float(v.x),
                                              __uint_as_float(v.z));
                    }
                }
                __syncthreads();
            }
        }

        // ---- out burst: 8 stores, in flight during next block's matvec#0,
        //      drained by its k==0 drain — never poisons a poll ----
        if (myrow >= 0) {
#pragma unroll
            for (int k = 0; k < KB; ++k)
                out[(size_t)(tb + k) * NN + myrow] = xnb[k];
        }
    }
}

extern "C" void kernel_launch(void* const* d_in, const int* in_sizes, int n_in,
                              void* d_out, int out_size, void* d_ws, size_t ws_size,
                              hipStream_t stream) {
    const float* sc = (const float*)d_in[0];
    const float* x0 = (const float*)d_in[1];
    const float* y0 = (const float*)d_in[2];
    const float* aa = (const float*)d_in[3];
    const float* om = (const float*)d_in[4];
    const float* nz = (const float*)d_in[5];
    const float* gg = (const float*)d_in[6];
    float* out = (float*)d_out;

    u32x4* pub = (u32x4*)d_ws;   // 2*NPAD*16 = 16 KB

    hipLaunchKernelGGL(hopf_init_ws, dim3(1), dim3(1024), 0, stream, pub);
    hipLaunchKernelGGL(hopf_main, dim3(NBLK), dim3(TPB), 0, stream,
                       sc, x0, y0, aa, om, nz, gg, out, pub);
}

// Round 15
// 42949.734 us; speedup vs baseline: 1.0187x; 1.0187x over previous
//
#include <hip/hip_runtime.h>

#define NN    500
#define TT    20000
#define NPAD  512
#define NBLK  8
#define NROW  64        // padded rows per block
#define TPB   512
#define RPT   4         // rows per thread
#define CPT   16        // cols per thread (strided by 32)
#define DTC   0.05f
#define SQDTC 0.22360679774997896f

typedef unsigned int u32x4 __attribute__((ext_vector_type(4)));

// ---------------------------------------------------------------------------
// Publish via atomic swaps: atomics execute AT the coherence point — they
// cannot linger in write-coalescing buffers like plain stores can. Two 8B
// halves, each carrying (data, tag): both-tags-fresh => both halves landed.
// ---------------------------------------------------------------------------
__device__ __forceinline__ void publish_atomic(u32x4* p, u32x4 v) {
    unsigned long long lo = ((unsigned long long)v.y << 32) | (unsigned long long)v.x;
    unsigned long long hi = ((unsigned long long)v.w << 32) | (unsigned long long)v.z;
    unsigned long long* q = (unsigned long long*)p;
    asm volatile("global_atomic_swap_x2 %0, %1, off" :: "v"(q),     "v"(lo) : "memory");
    asm volatile("global_atomic_swap_x2 %0, %1, off" :: "v"(q + 1), "v"(hi) : "memory");
}
__device__ __forceinline__ u32x4 load_coh_u128(const u32x4* p) {
    u32x4 v;
    asm volatile("global_load_dwordx4 %0, %1, off sc0 sc1\n\t"
                 "s_waitcnt vmcnt(0)" : "=v"(v) : "v"(p) : "memory");
    return v;
}

// ws layout: pub[2][NPAD] of u32x4 = 16 KB
__global__ __launch_bounds__(1024) void hopf_init_ws(u32x4* pub) {
    int i = blockIdx.x * blockDim.x + threadIdx.x;
    if (i < 2 * NPAD) pub[i] = (u32x4){0u, 0u, 0u, 0u};
}

__global__ __launch_bounds__(TPB) void hopf_main(
    const float* __restrict__ sc, const float* __restrict__ x0,
    const float* __restrict__ y0, const float* __restrict__ aa,
    const float* __restrict__ om, const float* __restrict__ noise,
    const float* __restrict__ gg, float* __restrict__ out,
    u32x4* __restrict__ pub)
{
    const int tid  = threadIdx.x;
    const int blk  = blockIdx.x;
    const int cgrp = tid & 31;       // 32 column groups
    const int rgrp = tid >> 5;       // 16 row groups of RPT rows
    const int r0   = blk * NROW + rgrp * RPT;   // padded global row base

    __shared__ __align__(16) float2 xy[NPAD];   // full padded state (x,y)

    // ---- sc slice -> registers.  col(c) = cgrp + 32*c ----
    float scr[RPT][CPT];
#pragma unroll
    for (int r = 0; r < RPT; ++r) {
        int row = r0 + r;
#pragma unroll
        for (int c = 0; c < CPT; ++c) {
            int col = cgrp + 32 * c;
            scr[r][c] = (row < NN && col < NN) ? sc[row * NN + col] : 0.0f;
        }
    }

    // ---- deg per row ----
    float dsum[RPT];
#pragma unroll
    for (int r = 0; r < RPT; ++r) {
        float s = 0.f;
#pragma unroll
        for (int c = 0; c < CPT; ++c) s += scr[r][c];
        dsum[r] = s;
    }
#pragma unroll
    for (int m = 16; m >= 1; m >>= 1) {
#pragma unroll
        for (int r = 0; r < RPT; ++r) dsum[r] += __shfl_xor(dsum[r], m, 32);
    }

    // ---- pin the sc slice (optimizer cannot demote/rematerialize) ----
#pragma unroll
    for (int r = 0; r < RPT; ++r)
#pragma unroll
        for (int c = 0; c < CPT; ++c)
            asm volatile("" : "+v"(scr[r][c]));

    // ---- per-finalize-lane constants (lanes cgrp<RPT own row r0+cgrp) ----
    float a_i = 0.f, om_i = 0.f, deg_i = 0.f;
    int myrow = -1;
    if (cgrp < RPT) {
        int row = r0 + cgrp;
        deg_i = (cgrp == 0) ? dsum[0] : (cgrp == 1) ? dsum[1]
              : (cgrp == 2) ? dsum[2] : dsum[3];
        if (row < NN) { myrow = row; a_i = aa[row]; om_i = om[row]; }
    }
    const float g = gg[0];

    // ---- initial state into LDS (pad rows stay zero forever) ----
    xy[tid] = (tid < NN) ? make_float2(x0[tid], y0[tid]) : make_float2(0.f, 0.f);
    __syncthreads();

    // prefetched noise for step 0
    float2 nz = make_float2(0.f, 0.f);
    if (myrow >= 0) nz = *(const float2*)(noise + 2 * (size_t)myrow);

    for (int t = 0; t < TT; ++t) {
        const int p = t & 1;
        // prefetch next step's noise (hidden under the matvec)
        float2 nz_next = make_float2(0.f, 0.f);
        if (myrow >= 0 && t + 1 < TT)
            nz_next = *(const float2*)(noise + (size_t)(t + 1) * (2 * NN) + 2 * (size_t)myrow);

        // ---- partial matvec: 4 rows x 16 strided cols per thread ----
        float2 acc[RPT];
#pragma unroll
        for (int r = 0; r < RPT; ++r) acc[r] = make_float2(0.f, 0.f);
#pragma unroll
        for (int c = 0; c < CPT; ++c) {
            float2 w = xy[cgrp + 32 * c];
#pragma unroll
            for (int r = 0; r < RPT; ++r) {
                acc[r].x += scr[r][c] * w.x;
                acc[r].y += scr[r][c] * w.y;
            }
        }
        // ---- reduce across the 32 column-group lanes ----
#pragma unroll
        for (int m = 16; m >= 1; m >>= 1) {
#pragma unroll
            for (int r = 0; r < RPT; ++r) {
                acc[r].x += __shfl_xor(acc[r].x, m, 32);
                acc[r].y += __shfl_xor(acc[r].y, m, 32);
            }
        }

        // ---- finalize + publish via atomics (lanes cgrp<RPT) ----
        if (myrow >= 0) {
            float sx = (cgrp == 0) ? acc[0].x : (cgrp == 1) ? acc[1].x
                     : (cgrp == 2) ? acc[2].x : acc[3].x;
            float sy = (cgrp == 0) ? acc[0].y : (cgrp == 1) ? acc[1].y
                     : (cgrp == 2) ? acc[2].y : acc[3].y;
            float2 cur = xy[myrow];
            float r2 = cur.x * cur.x + cur.y * cur.y;
            float cx = sx - deg_i * cur.x;
            float cy = sy - deg_i * cur.y;
            float dx = (a_i - r2) * cur.x - om_i * cur.y + g * cx;
            float dy = (a_i - r2) * cur.y + om_i * cur.x + g * cy;
            float xn = cur.x + DTC * dx + SQDTC * nz.x;
            float yn = cur.y + DTC * dy + SQDTC * nz.y;
            out[(size_t)t * NN + myrow] = xn;
            u32x4 pkt = { __float_as_uint(xn), (unsigned)(t + 1),
                          __float_as_uint(yn), (unsigned)(t + 1) };
            publish_atomic(&pub[(size_t)p * NPAD + myrow], pkt);
        }
        nz = nz_next;

        if (t == TT - 1) break;   // uniform across grid

        // protect xy: all matvec/finalize reads done before overwrite
        __syncthreads();

        // ---- gather: single-outstanding poll of own tagged slot.
        //      ONLY real rows — padding rows are never published. ----
        if (tid < NN) {
            const u32x4* slot = &pub[(size_t)p * NPAD + tid];
            u32x4 v;
            do {
                v = load_coh_u128(slot);
            } while ((int)v.y < t + 1 || (int)v.w < t + 1);
            xy[tid] = make_float2(__uint_as_float(v.x), __uint_as_float(v.z));
        }
        __syncthreads();
    }
}

extern "C" void kernel_launch(void* const* d_in, const int* in_sizes, int n_in,
                              void* d_out, int out_size, void* d_ws, size_t ws_size,
                              hipStream_t stream) {
    const float* sc = (const float*)d_in[0];
    const float* x0 = (const float*)d_in[1];
    const float* y0 = (const float*)d_in[2];
    const float* aa = (const float*)d_in[3];
    const float* om = (const float*)d_in[4];
    const float* nz = (const float*)d_in[5];
    const float* gg = (const float*)d_in[6];
    float* out = (float*)d_out;

    u32x4* pub = (u32x4*)d_ws;   // 2*NPAD*16 = 16 KB

    hipLaunchKernelGGL(hopf_init_ws, dim3(1), dim3(1024), 0, stream, pub);
    hipLaunchKernelGGL(hopf_main, dim3(NBLK), dim3(TPB), 0, stream,
                       sc, x0, y0, aa, om, nz, gg, out, pub);
}